// Round 8
// baseline (274.921 us; speedup 1.0000x reference)
//
#include <hip/hip_runtime.h>
#include <math.h>

// Capsule dynamic routing, MI355X. Round 8: 5-dispatch chain, all-fp32.
//   logits[b,j,n] = u[b,n,:] . V[b,j,:],  V[b,j,k] = sum_d W[k,jd]*o[b,j,d]
//   o[b,j,d]      = sum_k G[b,j,k]*W[k,jd], G[b,j,k] = sum_n c[b,j,n]*u[b,n,k]
// iter0: c uniform 0.1 -> o0 = 0.1*(colsum u)@W.
// R8 vs R7 (which regressed to 229 us at 14.6% occupancy):
//  - routes use 2 threads/row (shfl_xor combine) + 128-row tiles -> 1024
//    blocks, 16 waves/CU (2x R5, 4x R7's effective hiding).
//  - V produced by separate tiny kernels again; routes read it through a
//    never-written const __restrict__ pointer (R5's fast scalar path).
//  - keep R7's working last-block squash fusion in route pass 1.

#define BATCH 64
#define NN    2048
#define KD    128
#define JCAP  10
#define DCAP  16
#define JDIM  160
#define EPSQ  1e-7f
#define TPB   256
#define RT    16          // route tiles per batch (128 rows each)
#define RROWS 128

// ws layout (float offsets):
//  Sp  [64][8][128]     @ 0         (65536)
//  Gp1 [64][16][1280]   @ 65536     (1310720)
//  O2p [64][16][160]    @ 1376256   (163840)
//  V0  [64][10][128]    @ 1540096   (81920)
//  V1  [64][10][128]    @ 1622016   (81920)
//  cnt [64] uint        @ 1703936
#define WS_SP   0
#define WS_GP1  65536
#define WS_O2P  1376256
#define WS_V0   1540096
#define WS_V1   1622016
#define WS_CNT  1703936

// ---- K1: colsum partials Sp (fp32, 8x 256-row tiles) + zero counters ----
__global__ __launch_bounds__(TPB) void k_prep(const float* __restrict__ u,
                                              float* __restrict__ Sp,
                                              unsigned int* __restrict__ cnt) {
  const int b = blockIdx.y, tile = blockIdx.x, t = threadIdx.x;
  if (b == 0 && tile == 0 && t < BATCH) cnt[t] = 0u;
  const int k4 = (t & 31) * 4, rg = t >> 5;
  __shared__ float4 red[256];
  const float* p = u + ((size_t)(b * NN) + tile * 256 + rg * 32) * KD + k4;
  float4 a = make_float4(0.f, 0.f, 0.f, 0.f);
#pragma unroll 4
  for (int r = 0; r < 32; ++r) {
    float4 w = *(const float4*)(p + (size_t)r * KD);
    a.x += w.x; a.y += w.y; a.z += w.z; a.w += w.w;
  }
  red[t] = a;
  __syncthreads();
  if (t < 32) {
    float4 s4 = red[t];
#pragma unroll
    for (int rg2 = 1; rg2 < 8; ++rg2) {
      float4 w = red[rg2 * 32 + t];
      s4.x += w.x; s4.y += w.y; s4.z += w.z; s4.w += w.w;
    }
    *(float4*)&Sp[(size_t)(b * 8 + tile) * KD + t * 4] = s4;
  }
}

// ---- K2/K4: fold partials -> o = Gsum@W -> V (global) ----
__global__ __launch_bounds__(TPB) void k_makeV(const float* __restrict__ ws,
                                               const float* __restrict__ W,
                                               float* __restrict__ V,
                                               int pass) {
  const int b = blockIdx.x, t = threadIdx.x;
  __shared__ float gsum[JCAP * KD];   // pass0 uses first 128 only
  __shared__ float o_s[JDIM];
  if (pass == 0) {
    const float* SpB = ws + WS_SP + (size_t)b * 8 * KD;
    if (t < KD) {
      float s = 0.f;
#pragma unroll
      for (int tl = 0; tl < 8; ++tl) s += SpB[tl * KD + t];
      gsum[t] = s * 0.1f;
    }
  } else {
    const float* GpB = ws + WS_GP1 + (size_t)b * RT * (JCAP * KD);
    for (int i = t; i < JCAP * KD; i += TPB) {
      float s = 0.f;
#pragma unroll
      for (int tl = 0; tl < RT; ++tl) s += GpB[(size_t)tl * (JCAP * KD) + i];
      gsum[i] = s;
    }
  }
  __syncthreads();
  if (t < JDIM) {
    const int j = t >> 4;
    const float* gs = pass == 0 ? gsum : (gsum + j * KD);
    float acc = 0.f;
#pragma unroll 4
    for (int k = 0; k < KD; ++k) acc += gs[k] * W[k * JDIM + t];
    o_s[t] = acc;
  }
  __syncthreads();
  const int k = t & 127, gg = t >> 7;
#pragma unroll
  for (int i = 0; i < 5; ++i) {
    const int j = gg * 5 + i;
    const float* wp = W + k * JDIM + j * DCAP;
    float acc = 0.f;
#pragma unroll
    for (int d = 0; d < DCAP; ++d) acc += wp[d] * o_s[j * DCAP + d];
    V[(size_t)(b * JCAP + j) * KD + k] = acc;
  }
}

// ---- K3/K5: route pass. 128-row tiles, 1024 blocks, 2 threads/row ----
// pass0: dst = Gp1 partials [b][tile][1280]
// pass1: dst = O2p partials [b][tile][160]; last block/batch squashes -> out
__global__ __launch_bounds__(TPB) void k_route(const float* __restrict__ u,
                                               const float* __restrict__ V,
                                               const float* __restrict__ W,
                                               float* __restrict__ dst,
                                               float* __restrict__ out,
                                               unsigned int* __restrict__ cnt,
                                               int pass) {
  const int b = blockIdx.y, tile = blockIdx.x, t = threadIdx.x;
  const int r0 = tile * RROWS;
  __shared__ __align__(16) float Cs[JCAP][RROWS + 4];   // 5.2 KB
  __shared__ __align__(16) float Gp[4][JCAP][KD];       // 20 KB
  __shared__ float o_s[JDIM];
  __shared__ float sc[JCAP];
  __shared__ unsigned int lastflag;

  // ---- phase 1: 2 threads per row (each 64 k's), shfl_xor combine ----
  {
    const int row = t >> 1, h = t & 1;
    const float* up = u + (size_t)(b * NN + r0 + row) * KD + h * 64;
    const float* vb = V + (size_t)b * (JCAP * KD) + h * 64;  // never written here
    float acc[JCAP];
#pragma unroll
    for (int j = 0; j < JCAP; ++j) acc[j] = 0.f;
    for (int kc = 0; kc < 64; kc += 8) {
      float4 xa = *(const float4*)(up + kc);
      float4 xb = *(const float4*)(up + kc + 4);
#pragma unroll
      for (int j = 0; j < JCAP; ++j) {
        float4 v0 = *(const float4*)(vb + j * KD + kc);
        float4 v1 = *(const float4*)(vb + j * KD + kc + 4);
        acc[j] += xa.x * v0.x + xa.y * v0.y + xa.z * v0.z + xa.w * v0.w
                + xb.x * v1.x + xb.y * v1.y + xb.z * v1.z + xb.w * v1.w;
      }
    }
#pragma unroll
    for (int j = 0; j < JCAP; ++j) acc[j] += __shfl_xor(acc[j], 1, 64);
    float m = acc[0];
#pragma unroll
    for (int j = 1; j < JCAP; ++j) m = fmaxf(m, acc[j]);
    float s = 0.f;
#pragma unroll
    for (int j = 0; j < JCAP; ++j) { acc[j] = __expf(acc[j] - m); s += acc[j]; }
    const float inv = 1.f / s;
    if (h == 0) {
#pragma unroll
      for (int j = 0; j < JCAP; ++j) Cs[j][row] = acc[j] * inv;
    }
  }
  __syncthreads();

  // ---- phase 2: wave = 32 rows, lane = k-pair (coalesced u reads) ----
  {
    const int wave = t >> 6, lane = t & 63;
    const int rw = wave * 32;
    float g0[JCAP], g1[JCAP];
#pragma unroll
    for (int j = 0; j < JCAP; ++j) { g0[j] = 0.f; g1[j] = 0.f; }
    const float* ub = u + (size_t)(b * NN + r0 + rw) * KD + 2 * lane;
    for (int rc = 0; rc < 32; rc += 4) {
      float ua[4], uc[4];
#pragma unroll
      for (int q = 0; q < 4; ++q) {
        float2 w = *(const float2*)(ub + (size_t)(rc + q) * KD);
        ua[q] = w.x; uc[q] = w.y;
      }
#pragma unroll
      for (int j = 0; j < JCAP; ++j) {
        float4 c4 = *(const float4*)&Cs[j][rw + rc];
        g0[j] += c4.x * ua[0] + c4.y * ua[1] + c4.z * ua[2] + c4.w * ua[3];
        g1[j] += c4.x * uc[0] + c4.y * uc[1] + c4.z * uc[2] + c4.w * uc[3];
      }
    }
#pragma unroll
    for (int j = 0; j < JCAP; ++j)
      *(float2*)&Gp[wave][j][2 * lane] = make_float2(g0[j], g1[j]);
  }
  __syncthreads();

  if (pass == 0) {
    float* g1d = dst + (size_t)(b * RT + tile) * (JCAP * KD);
    for (int i = t; i < JCAP * KD; i += TPB)
      g1d[i] = Gp[0][0][i] + Gp[1][0][i] + Gp[2][0][i] + Gp[3][0][i];
    return;
  }

  // ---- pass 1 tail: O2 partial -> counter -> last block squashes ----
  for (int i = t; i < JCAP * KD; i += TPB)
    Gp[0][0][i] = Gp[0][0][i] + Gp[1][0][i] + Gp[2][0][i] + Gp[3][0][i];
  __syncthreads();
  if (t < JDIM) {
    const int j = t >> 4;
    float acc = 0.f;
#pragma unroll 4
    for (int k = 0; k < KD; ++k) acc += Gp[0][j][k] * W[k * JDIM + t];
    dst[(size_t)(b * RT + tile) * JDIM + t] = acc;
  }
  __syncthreads();
  if (t == 0) {
    __threadfence();                       // publish O2 partial
    lastflag = atomicAdd(&cnt[b], 1u);     // RT-1 => we are the last block
  }
  __syncthreads();
  if (lastflag != RT - 1u) return;
  __threadfence();                         // acquire others' partials

  const float* p = dst + (size_t)b * RT * JDIM;
  if (t < JDIM) {
    float s = 0.f;
#pragma unroll
    for (int tl = 0; tl < RT; ++tl) s += p[tl * JDIM + t];
    o_s[t] = s;
  }
  __syncthreads();
  if (t < JCAP) {
    float s2 = 0.f;
#pragma unroll
    for (int d = 0; d < DCAP; ++d) { float x = o_s[t * DCAP + d]; s2 += x * x; }
    sc[t] = s2 / ((1.f + s2) * sqrtf(s2 + EPSQ));
  }
  __syncthreads();
  if (t < JDIM) out[b * JDIM + t] = o_s[t] * sc[t >> 4];
}

extern "C" void kernel_launch(void* const* d_in, const int* in_sizes, int n_in,
                              void* d_out, int out_size, void* d_ws, size_t ws_size,
                              hipStream_t stream) {
  const float* u = (const float*)d_in[0];   // (64,2048,128) fp32
  const float* W = (const float*)d_in[1];   // (128,160) fp32
  float* out = (float*)d_out;               // (64,10,16) fp32
  float* ws  = (float*)d_ws;

  float* Sp  = ws + WS_SP;
  float* Gp1 = ws + WS_GP1;
  float* O2p = ws + WS_O2P;
  float* V0  = ws + WS_V0;
  float* V1  = ws + WS_V1;
  unsigned int* cnt = (unsigned int*)(ws + WS_CNT);

  k_prep <<<dim3(8, BATCH), TPB, 0, stream>>>(u, Sp, cnt);
  k_makeV<<<BATCH, TPB, 0, stream>>>(ws, W, V0, 0);
  k_route<<<dim3(RT, BATCH), TPB, 0, stream>>>(u, V0, W, Gp1, out, cnt, 0);
  k_makeV<<<BATCH, TPB, 0, stream>>>(ws, W, V1, 1);
  k_route<<<dim3(RT, BATCH), TPB, 0, stream>>>(u, V1, W, O2p, out, cnt, 1);
}

// Round 10
// 195.202 us; speedup vs baseline: 1.4084x; 1.4084x over previous
//
#include <hip/hip_runtime.h>
#include <math.h>

// Capsule dynamic routing, MI355X. Round 10 (= R9 resubmit after infra
// timeout): R5's proven route structure + R7's proven last-block squash
// fusion. 5 dispatches, all-fp32.
//   logits[b,j,n] = u[b,n,:] . V[b,j,:],  V[b,j,k] = sum_d W[k,jd]*o[b,j,d]
//   o[b,j,d]      = sum_k G[b,j,k]*W[k,jd], G[b,j,k] = sum_n c[b,j,n]*u[b,n,k]
// iter0: c uniform 0.1 -> o0 = 0.1*(colsum u)@W.
// HARD-WON RULES (R7/R8 regressions):
//  - Phase-1 V reads MUST be wave-uniform addresses through a const
//    __restrict__ pointer that this kernel never writes -> s_load path.
//    (R7: same-kernel vector write of V killed it; R8: lane-dependent
//    V address killed it. Both ~2.5x slower.)
//  - All-fp32 math (R6: bf16 u fails the 2% threshold).

#define BATCH 64
#define NN    2048
#define KD    128
#define JCAP  10
#define DCAP  16
#define JDIM  160
#define EPSQ  1e-7f
#define TPB   256

// ws layout (float offsets):
//  Sp  [64][8][128]    @ 0       (65536)
//  Gp1 [64][8][1280]   @ 65536   (655360)
//  O2p [64][8][160]    @ 720896  (81920)
//  V0  [64][10][128]   @ 802816  (81920)
//  V1  [64][10][128]   @ 884736  (81920)
//  cnt [64] uint       @ 966656
#define WS_SP   0
#define WS_GP1  65536
#define WS_O2P  720896
#define WS_V0   802816
#define WS_V1   884736
#define WS_CNT  966656

// ---- K1: colsum partials Sp + zero counters ----------------------------
__global__ __launch_bounds__(TPB) void k_prep(const float* __restrict__ u,
                                              float* __restrict__ Sp,
                                              unsigned int* __restrict__ cnt) {
  const int b = blockIdx.y, tile = blockIdx.x, t = threadIdx.x;
  if (b == 0 && tile == 0 && t < BATCH) cnt[t] = 0u;
  const int k4 = (t & 31) * 4, rg = t >> 5;
  __shared__ float4 red[256];
  const float* p = u + ((size_t)(b * NN) + tile * 256 + rg * 32) * KD + k4;
  float4 a = make_float4(0.f, 0.f, 0.f, 0.f);
#pragma unroll 4
  for (int r = 0; r < 32; ++r) {
    float4 w = *(const float4*)(p + (size_t)r * KD);
    a.x += w.x; a.y += w.y; a.z += w.z; a.w += w.w;
  }
  red[t] = a;
  __syncthreads();
  if (t < 32) {
    float4 s4 = red[t];
#pragma unroll
    for (int rg2 = 1; rg2 < 8; ++rg2) {
      float4 w = red[rg2 * 32 + t];
      s4.x += w.x; s4.y += w.y; s4.z += w.z; s4.w += w.w;
    }
    *(float4*)&Sp[(size_t)(b * 8 + tile) * KD + t * 4] = s4;
  }
}

// ---- K2/K4: fold partials -> o = Gsum@W -> V (global) ------------------
__global__ __launch_bounds__(TPB) void k_makeV(const float* __restrict__ ws,
                                               const float* __restrict__ W,
                                               float* __restrict__ V,
                                               int pass) {
  const int b = blockIdx.x, t = threadIdx.x;
  __shared__ float gsum[JCAP * KD];   // pass0 uses first 128 only
  __shared__ float o_s[JDIM];
  if (pass == 0) {
    const float* SpB = ws + WS_SP + (size_t)b * 8 * KD;
    if (t < KD) {
      float s = 0.f;
#pragma unroll
      for (int tl = 0; tl < 8; ++tl) s += SpB[tl * KD + t];
      gsum[t] = s * 0.1f;
    }
  } else {
    const float* GpB = ws + WS_GP1 + (size_t)b * 8 * (JCAP * KD);
    for (int i = t; i < JCAP * KD; i += TPB) {
      float s = 0.f;
#pragma unroll
      for (int tl = 0; tl < 8; ++tl) s += GpB[(size_t)tl * (JCAP * KD) + i];
      gsum[i] = s;
    }
  }
  __syncthreads();
  if (t < JDIM) {
    const int j = t >> 4;
    const float* gs = pass == 0 ? gsum : (gsum + j * KD);
    float acc = 0.f;
#pragma unroll 4
    for (int k = 0; k < KD; ++k) acc += gs[k] * W[k * JDIM + t];
    o_s[t] = acc;
  }
  __syncthreads();
  const int k = t & 127, gg = t >> 7;
#pragma unroll
  for (int i = 0; i < 5; ++i) {
    const int j = gg * 5 + i;
    const float* wp = W + k * JDIM + j * DCAP;
    float acc = 0.f;
#pragma unroll
    for (int d = 0; d < DCAP; ++d) acc += wp[d] * o_s[j * DCAP + d];
    V[(size_t)(b * JCAP + j) * KD + k] = acc;
  }
}

// ---- K3/K5: route pass (R5 structure). 256-row tiles, 512 blocks ------
// pass0: dst = Gp1 partials [b][tile][1280]
// pass1: dst = O2p partials [b][tile][160]; last block/batch squashes.
__global__ __launch_bounds__(TPB) void k_route(const float* __restrict__ u,
                                               const float* __restrict__ V,
                                               const float* __restrict__ W,
                                               float* __restrict__ dst,
                                               float* __restrict__ out,
                                               unsigned int* __restrict__ cnt,
                                               int pass) {
  const int b = blockIdx.y, tile = blockIdx.x, t = threadIdx.x;
  const int r0 = tile * 256;
  __shared__ __align__(16) float Cs[JCAP][260];
  __shared__ __align__(16) float Gp[4][JCAP][KD];
  __shared__ float o_s[JDIM];
  __shared__ float sc[JCAP];
  __shared__ unsigned int lastflag;

  // phase 1: thread = row; V reads wave-uniform -> s_loads (NEVER break this)
  {
    const float* up = u + (size_t)(b * NN + r0 + t) * KD;
    const float* vb = V + (size_t)(b * JCAP) * KD;
    float acc[JCAP];
#pragma unroll
    for (int j = 0; j < JCAP; ++j) acc[j] = 0.f;
    for (int kc = 0; kc < KD; kc += 8) {
      float4 xa = *(const float4*)(up + kc);
      float4 xb = *(const float4*)(up + kc + 4);
#pragma unroll
      for (int j = 0; j < JCAP; ++j) {
        float4 v0 = *(const float4*)(vb + j * KD + kc);
        float4 v1 = *(const float4*)(vb + j * KD + kc + 4);
        acc[j] += xa.x * v0.x + xa.y * v0.y + xa.z * v0.z + xa.w * v0.w
                + xb.x * v1.x + xb.y * v1.y + xb.z * v1.z + xb.w * v1.w;
      }
    }
    float m = acc[0];
#pragma unroll
    for (int j = 1; j < JCAP; ++j) m = fmaxf(m, acc[j]);
    float s = 0.f;
#pragma unroll
    for (int j = 0; j < JCAP; ++j) { acc[j] = __expf(acc[j] - m); s += acc[j]; }
    const float inv = 1.f / s;
#pragma unroll
    for (int j = 0; j < JCAP; ++j) Cs[j][t] = acc[j] * inv;
  }
  __syncthreads();

  // phase 2: wave = 64 rows, lane = k-pair (coalesced u reads)
  {
    const int wave = t >> 6, lane = t & 63;
    const int rw = wave * 64;
    float g0[JCAP], g1[JCAP];
#pragma unroll
    for (int j = 0; j < JCAP; ++j) { g0[j] = 0.f; g1[j] = 0.f; }
    const float* ub = u + (size_t)(b * NN + r0 + rw) * KD + 2 * lane;
    for (int rc = 0; rc < 64; rc += 4) {
      float ua[4], uc[4];
#pragma unroll
      for (int q = 0; q < 4; ++q) {
        float2 w = *(const float2*)(ub + (size_t)(rc + q) * KD);
        ua[q] = w.x; uc[q] = w.y;
      }
#pragma unroll
      for (int j = 0; j < JCAP; ++j) {
        float4 c4 = *(const float4*)&Cs[j][rw + rc];
        g0[j] += c4.x * ua[0] + c4.y * ua[1] + c4.z * ua[2] + c4.w * ua[3];
        g1[j] += c4.x * uc[0] + c4.y * uc[1] + c4.z * uc[2] + c4.w * uc[3];
      }
    }
#pragma unroll
    for (int j = 0; j < JCAP; ++j)
      *(float2*)&Gp[wave][j][2 * lane] = make_float2(g0[j], g1[j]);
  }
  __syncthreads();

  if (pass == 0) {
    float* g1d = dst + (size_t)(b * 8 + tile) * (JCAP * KD);
    for (int i = t; i < JCAP * KD; i += TPB)
      g1d[i] = Gp[0][0][i] + Gp[1][0][i] + Gp[2][0][i] + Gp[3][0][i];
    return;
  }

  // pass 1 tail: O2 partial -> counter -> last block squashes
  for (int i = t; i < JCAP * KD; i += TPB)
    Gp[0][0][i] = Gp[0][0][i] + Gp[1][0][i] + Gp[2][0][i] + Gp[3][0][i];
  __syncthreads();
  if (t < JDIM) {
    const int j = t >> 4;
    float acc = 0.f;
#pragma unroll 4
    for (int k = 0; k < KD; ++k) acc += Gp[0][j][k] * W[k * JDIM + t];
    dst[(size_t)(b * 8 + tile) * JDIM + t] = acc;
  }
  __syncthreads();
  if (t == 0) {
    __threadfence();                       // publish O2 partial
    lastflag = atomicAdd(&cnt[b], 1u);     // 7 => we are the last block
  }
  __syncthreads();
  if (lastflag != 7u) return;
  __threadfence();                         // acquire others' partials

  const float* p = dst + (size_t)b * 8 * JDIM;
  if (t < JDIM) {
    float s = 0.f;
#pragma unroll
    for (int tl = 0; tl < 8; ++tl) s += p[tl * JDIM + t];
    o_s[t] = s;
  }
  __syncthreads();
  if (t < JCAP) {
    float s2 = 0.f;
#pragma unroll
    for (int d = 0; d < DCAP; ++d) { float x = o_s[t * DCAP + d]; s2 += x * x; }
    sc[t] = s2 / ((1.f + s2) * sqrtf(s2 + EPSQ));
  }
  __syncthreads();
  if (t < JDIM) out[b * JDIM + t] = o_s[t] * sc[t >> 4];
}

extern "C" void kernel_launch(void* const* d_in, const int* in_sizes, int n_in,
                              void* d_out, int out_size, void* d_ws, size_t ws_size,
                              hipStream_t stream) {
  const float* u = (const float*)d_in[0];   // (64,2048,128) fp32
  const float* W = (const float*)d_in[1];   // (128,160) fp32
  float* out = (float*)d_out;               // (64,10,16) fp32
  float* ws  = (float*)d_ws;

  float* Sp  = ws + WS_SP;
  float* Gp1 = ws + WS_GP1;
  float* O2p = ws + WS_O2P;
  float* V0  = ws + WS_V0;
  float* V1  = ws + WS_V1;
  unsigned int* cnt = (unsigned int*)(ws + WS_CNT);

  k_prep <<<dim3(8, BATCH), TPB, 0, stream>>>(u, Sp, cnt);
  k_makeV<<<BATCH, TPB, 0, stream>>>(ws, W, V0, 0);
  k_route<<<dim3(8, BATCH), TPB, 0, stream>>>(u, V0, W, Gp1, out, cnt, 0);
  k_makeV<<<BATCH, TPB, 0, stream>>>(ws, W, V1, 1);
  k_route<<<dim3(8, BATCH), TPB, 0, stream>>>(u, V1, W, O2p, out, cnt, 1);
}